// Round 1
// 751.224 us; speedup vs baseline: 1.0873x; 1.0873x over previous
//
#include <hip/hip_runtime.h>
#include <math.h>

#define H 1024
#define V 50257
#define S 2048

typedef unsigned short u16;
typedef __attribute__((ext_vector_type(8))) short short8;
typedef __attribute__((ext_vector_type(4))) float floatx4;

__device__ __forceinline__ float b2f(u16 b) {
    union { unsigned int u; float f; } x; x.u = ((unsigned int)b) << 16; return x.f;
}
__device__ __forceinline__ u16 f2b(float f) {
    union { float f; unsigned int u; } x; x.f = f;
    unsigned int r = x.u + 0x7FFFu + ((x.u >> 16) & 1u);
    return (u16)(r >> 16);
}

// ---------------------------------------------------------------------------
// Generic f32 matvec (used for comb): out[r] = act( W[r,:].[xa;xb] + b1[r] )
// ---------------------------------------------------------------------------
__global__ void __launch_bounds__(256) matvec_kernel(
    const float* __restrict__ W,
    const float* __restrict__ xa, const int* __restrict__ xa_idx, int Ka,
    const float* __restrict__ xb, int Kb,
    const float* __restrict__ bias1,
    float* __restrict__ out, int rows, int relu_flag)
{
    int wave = threadIdx.x >> 6;
    int lane = threadIdx.x & 63;
    int r = blockIdx.x * 4 + wave;
    if (r >= rows) return;
    const float* Wr = W + (size_t)r * (Ka + Kb);
    if (xa_idx) xa += (size_t)(*xa_idx) * Ka;
    float dot = 0.f;
    for (int base = 0; base < Ka; base += 256) {
        int k = base + lane * 4;
        float4 w4 = *reinterpret_cast<const float4*>(Wr + k);
        float4 a4 = *reinterpret_cast<const float4*>(xa + k);
        dot += w4.x * a4.x + w4.y * a4.y + w4.z * a4.z + w4.w * a4.w;
    }
    for (int base = 0; base < Kb; base += 256) {
        int k = base + lane * 4;
        float4 w4 = *reinterpret_cast<const float4*>(Wr + Ka + k);
        float4 a4 = *reinterpret_cast<const float4*>(xb + k);
        dot += w4.x * a4.x + w4.y * a4.y + w4.z * a4.z + w4.w * a4.w;
    }
    #pragma unroll
    for (int off = 32; off; off >>= 1) dot += __shfl_down(dot, off);
    if (lane == 0) {
        float v = dot + bias1[r];
        if (relu_flag) v = fmaxf(v, 0.f);
        out[r] = v;
    }
}

// ---------------------------------------------------------------------------
// Prep: all blocks: zero ws[0..4097) (attn_logits, cat, sumexp) via blocks 0-16.
//       blocks [0,256): u = Wa_w @ h0 + Wa_b + Ua_b (4 rows/block).
//       blocks [256,3328): split enc/Ua into bf16 hi/lo pairs.
// ---------------------------------------------------------------------------
__global__ void __launch_bounds__(256) prep_kernel(
    const float* __restrict__ Wa_w, const float* __restrict__ hidden,
    const float* __restrict__ Wa_b, const float* __restrict__ Ua_b,
    float* __restrict__ u_vec, float* __restrict__ ws_zero,
    const float* __restrict__ enc, const float* __restrict__ Ua,
    u16* __restrict__ enc_hi, u16* __restrict__ enc_lo,
    u16* __restrict__ Ua_hi, u16* __restrict__ Ua_lo)
{
    unsigned int zidx = blockIdx.x * 256 + threadIdx.x;
    if (zidx < 4097) ws_zero[zidx] = 0.f;

    if (blockIdx.x < 256) {
        int wave = threadIdx.x >> 6, lane = threadIdx.x & 63;
        int r = blockIdx.x * 4 + wave;
        const float* Wr = Wa_w + (size_t)r * H;
        float dot = 0.f;
        #pragma unroll
        for (int t = 0; t < 4; t++) {
            int k = t * 256 + lane * 4;
            float4 w4 = *reinterpret_cast<const float4*>(Wr + k);
            float4 a4 = *reinterpret_cast<const float4*>(hidden + k);
            dot += w4.x * a4.x + w4.y * a4.y + w4.z * a4.z + w4.w * a4.w;
        }
        #pragma unroll
        for (int off = 32; off; off >>= 1) dot += __shfl_down(dot, off);
        if (lane == 0) u_vec[r] = dot + Wa_b[r] + Ua_b[r];
        return;
    }
    int idx = (blockIdx.x - 256) * 1024 + threadIdx.x * 4; // 4 floats/thread
    const float* src; u16 *dhi, *dlo; int off;
    if (idx < S * H) { src = enc; dhi = enc_hi; dlo = enc_lo; off = idx; }
    else             { src = Ua;  dhi = Ua_hi;  dlo = Ua_lo;  off = idx - S * H; }
    float4 a = *reinterpret_cast<const float4*>(src + off);
    float av[4] = {a.x, a.y, a.z, a.w};
    ushort4 hi4, lo4;
    u16 hv[4], lv[4];
    #pragma unroll
    for (int i = 0; i < 4; i++) {
        u16 h = f2b(av[i]);
        hv[i] = h;
        lv[i] = f2b(av[i] - b2f(h));
    }
    hi4.x = hv[0]; hi4.y = hv[1]; hi4.z = hv[2]; hi4.w = hv[3];
    lo4.x = lv[0]; lo4.y = lv[1]; lo4.z = lv[2]; lo4.w = lv[3];
    *reinterpret_cast<ushort4*>(dhi + off) = hi4;
    *reinterpret_cast<ushort4*>(dlo + off) = lo4;
}

// ---------------------------------------------------------------------------
// Attention logits via split-bf16 MFMA. 256-thread blocks: 4 waves share one
// 64-j tile (identical B-frag addresses -> L1 hits); wave w covers s-subtile
// sgrp*128 + w*32. Grid: 16 s-groups x 16 j-tiles = 256 blocks.
// C/D mapping (m89): col = lane&15 (j), row = (lane>>4)*4+reg (s).
// ---------------------------------------------------------------------------
__global__ void __launch_bounds__(256) attn_scores_kernel(
    const u16* __restrict__ enc_hi, const u16* __restrict__ enc_lo,
    const u16* __restrict__ Ua_hi, const u16* __restrict__ Ua_lo,
    const float* __restrict__ va, const float* __restrict__ u,
    float* __restrict__ attn_logits)
{
    int sgrp  = blockIdx.x & 15;
    int jtile = blockIdx.x >> 4;
    int wave = threadIdx.x >> 6;
    int lane = threadIdx.x & 63;
    int l15 = lane & 15, quad = lane >> 4;
    int s0 = sgrp * 128 + wave * 32, j0 = jtile * 64;

    floatx4 zero4 = {0.f, 0.f, 0.f, 0.f};
    floatx4 acc[2][4];
    #pragma unroll
    for (int ra = 0; ra < 2; ra++)
        #pragma unroll
        for (int cb = 0; cb < 4; cb++) acc[ra][cb] = zero4;

    size_t aoff = (size_t)(s0 + l15) * H + quad * 8;
    size_t boff = (size_t)(j0 + l15) * H + quad * 8;

    for (int k0 = 0; k0 < H; k0 += 32) {
        short8 ah0 = *reinterpret_cast<const short8*>(enc_hi + aoff + k0);
        short8 al0 = *reinterpret_cast<const short8*>(enc_lo + aoff + k0);
        short8 ah1 = *reinterpret_cast<const short8*>(enc_hi + aoff + 16 * H + k0);
        short8 al1 = *reinterpret_cast<const short8*>(enc_lo + aoff + 16 * H + k0);
        #pragma unroll
        for (int cb = 0; cb < 4; cb++) {
            size_t bo = boff + (size_t)cb * 16 * H + k0;
            short8 bh = *reinterpret_cast<const short8*>(Ua_hi + bo);
            short8 bl = *reinterpret_cast<const short8*>(Ua_lo + bo);
            acc[0][cb] = __builtin_amdgcn_mfma_f32_16x16x32_bf16(ah0, bh, acc[0][cb], 0, 0, 0);
            acc[0][cb] = __builtin_amdgcn_mfma_f32_16x16x32_bf16(ah0, bl, acc[0][cb], 0, 0, 0);
            acc[0][cb] = __builtin_amdgcn_mfma_f32_16x16x32_bf16(al0, bh, acc[0][cb], 0, 0, 0);
            acc[1][cb] = __builtin_amdgcn_mfma_f32_16x16x32_bf16(ah1, bh, acc[1][cb], 0, 0, 0);
            acc[1][cb] = __builtin_amdgcn_mfma_f32_16x16x32_bf16(ah1, bl, acc[1][cb], 0, 0, 0);
            acc[1][cb] = __builtin_amdgcn_mfma_f32_16x16x32_bf16(al1, bh, acc[1][cb], 0, 0, 0);
        }
    }

    #pragma unroll
    for (int ra = 0; ra < 2; ra++) {
        #pragma unroll
        for (int reg = 0; reg < 4; reg++) {
            float p = 0.f;
            #pragma unroll
            for (int cb = 0; cb < 4; cb++) {
                int jj = j0 + cb * 16 + l15;
                p += va[jj] * tanhf(acc[ra][cb][reg] + u[jj]);
            }
            p += __shfl_xor(p, 1); p += __shfl_xor(p, 2);
            p += __shfl_xor(p, 4); p += __shfl_xor(p, 8);
            if (l15 == 0)
                atomicAdd(&attn_logits[s0 + ra * 16 + quad * 4 + reg], p);
        }
    }
}

// ---------------------------------------------------------------------------
// Fused softmax + context. Each of 128 blocks recomputes max/Z from the raw
// logits (8 KB, L2-hot, ~1 us fully parallel — replaces the serial 1-block
// softmax kernel + separate launch). Block 0 also writes attn_weights output.
// Then each block accumulates its 16-row s-chunk of context into cat[0:H].
// ---------------------------------------------------------------------------
__global__ void __launch_bounds__(256) softmax_context_kernel(
    const float* __restrict__ logits, const float* __restrict__ enc,
    float* __restrict__ ctx, float* __restrict__ attn_out)
{
    __shared__ float red[256];
    __shared__ float sw[16];
    int tid = threadIdx.x;
    float vals[8];
    float m = -1e30f;
    #pragma unroll
    for (int i = 0; i < 8; i++) { vals[i] = logits[tid + 256 * i]; m = fmaxf(m, vals[i]); }
    red[tid] = m; __syncthreads();
    for (int s = 128; s > 0; s >>= 1) {
        if (tid < s) red[tid] = fmaxf(red[tid], red[tid + s]);
        __syncthreads();
    }
    float gmax = red[0]; __syncthreads();
    float sum = 0.f;
    #pragma unroll
    for (int i = 0; i < 8; i++) { vals[i] = expf(vals[i] - gmax); sum += vals[i]; }
    red[tid] = sum; __syncthreads();
    for (int s = 128; s > 0; s >>= 1) {
        if (tid < s) red[tid] += red[tid + s];
        __syncthreads();
    }
    float inv = 1.f / red[0];

    if (blockIdx.x == 0) {
        #pragma unroll
        for (int i = 0; i < 8; i++) attn_out[tid + 256 * i] = vals[i] * inv;
    }

    int sbase = blockIdx.x * 16;
    if (tid < 16) sw[tid] = expf(logits[sbase + tid] - gmax) * inv;
    __syncthreads();

    int h = tid * 4;
    float p0 = 0.f, p1 = 0.f, p2 = 0.f, p3 = 0.f;
    #pragma unroll
    for (int i = 0; i < 16; i++) {
        float w = sw[i];
        float4 e = *reinterpret_cast<const float4*>(enc + (size_t)(sbase + i) * H + h);
        p0 = fmaf(w, e.x, p0); p1 = fmaf(w, e.y, p1);
        p2 = fmaf(w, e.z, p2); p3 = fmaf(w, e.w, p3);
    }
    atomicAdd(&ctx[h + 0], p0); atomicAdd(&ctx[h + 1], p1);
    atomicAdd(&ctx[h + 2], p2); atomicAdd(&ctx[h + 3], p3);
}

// ---------------------------------------------------------------------------
// Fused GRU: one wave per j. Computes all 6 dots (w_ih rows j,H+j,2H+j over x;
// w_hh rows over h0), reduces, applies gate math, writes h_new to cat[H:2H]
// and d_out hidden slot. Grid 256 x 256 threads (4 j per block).
// ---------------------------------------------------------------------------
__global__ void __launch_bounds__(256) gru_fused_kernel(
    const float* __restrict__ w_ih, const float* __restrict__ w_hh,
    const float* __restrict__ x, const float* __restrict__ h0,
    const float* __restrict__ b_ih, const float* __restrict__ b_hh,
    float* __restrict__ cat_hnew, float* __restrict__ out_hidden)
{
    int wave = threadIdx.x >> 6, lane = threadIdx.x & 63;
    int j = blockIdx.x * 4 + wave;
    float d[6] = {0.f, 0.f, 0.f, 0.f, 0.f, 0.f};
    #pragma unroll
    for (int t = 0; t < 4; t++) {
        int k = t * 256 + lane * 4;
        float4 xv = *reinterpret_cast<const float4*>(x + k);
        float4 hv = *reinterpret_cast<const float4*>(h0 + k);
        #pragma unroll
        for (int g = 0; g < 3; g++) {
            float4 wi = *reinterpret_cast<const float4*>(w_ih + (size_t)(g * H + j) * H + k);
            float4 wh = *reinterpret_cast<const float4*>(w_hh + (size_t)(g * H + j) * H + k);
            d[g]     += wi.x * xv.x + wi.y * xv.y + wi.z * xv.z + wi.w * xv.w;
            d[3 + g] += wh.x * hv.x + wh.y * hv.y + wh.z * hv.z + wh.w * hv.w;
        }
    }
    #pragma unroll
    for (int off = 32; off; off >>= 1)
        #pragma unroll
        for (int g = 0; g < 6; g++) d[g] += __shfl_down(d[g], off);
    if (lane == 0) {
        float i_r = d[0] + b_ih[j];
        float i_z = d[1] + b_ih[H + j];
        float i_n = d[2] + b_ih[2 * H + j];
        float h_r = d[3] + b_hh[j];
        float h_z = d[4] + b_hh[H + j];
        float h_n = d[5] + b_hh[2 * H + j];
        float r = 1.f / (1.f + expf(-(i_r + h_r)));
        float z = 1.f / (1.f + expf(-(i_z + h_z)));
        float n = tanhf(i_n + r * h_n);
        float hn = (1.f - z) * n + z * h0[j];
        cat_hnew[j] = hn;
        out_hidden[j] = hn;
    }
}

// ---------------------------------------------------------------------------
// Output projection: 412 MB of f32 weights — THE HBM-bound kernel.
// sum(exp) now reduced per-block via LDS and written NON-atomically to
// separtial[blockIdx] — removes the 8192-wave same-address atomic tail.
// ---------------------------------------------------------------------------
__global__ void __launch_bounds__(256) out_matvec_kernel(
    const float* __restrict__ Wout, const float* __restrict__ bout,
    const float* __restrict__ cat, float* __restrict__ logits,
    float* __restrict__ separtial)
{
    __shared__ float cs[2 * H];
    __shared__ float wred[4];
    for (int i = threadIdx.x; i < 2 * H; i += 256) cs[i] = cat[i];
    __syncthreads();
    int wave = threadIdx.x >> 6, lane = threadIdx.x & 63;
    float lsum = 0.f;
    for (int v = blockIdx.x * 4 + wave; v < V; v += gridDim.x * 4) {
        const float* Wr = Wout + (size_t)v * (2 * H);
        float dot = 0.f;
        #pragma unroll
        for (int t = 0; t < 8; t++) {
            int k = t * 256 + lane * 4;
            float4 w4 = *reinterpret_cast<const float4*>(Wr + k);
            dot += w4.x * cs[k] + w4.y * cs[k + 1] + w4.z * cs[k + 2] + w4.w * cs[k + 3];
        }
        #pragma unroll
        for (int off = 32; off; off >>= 1) dot += __shfl_down(dot, off);
        if (lane == 0) {
            dot += bout[v];
            logits[v] = dot;
            lsum += expf(dot);
        }
    }
    if (lane == 0) wred[wave] = lsum;
    __syncthreads();
    if (threadIdx.x == 0)
        separtial[blockIdx.x] = wred[0] + wred[1] + wred[2] + wred[3];
}

// ---------------------------------------------------------------------------
// Log-softmax finalize: each block tree-reduces the 2048 per-block partials
// (8 KB, L2-hot, fully parallel across blocks) then subtracts log(Z).
// ---------------------------------------------------------------------------
__global__ void __launch_bounds__(256) logsoftmax_kernel(
    float* __restrict__ logits, const float* __restrict__ separtial)
{
    __shared__ float red[256];
    int tid = threadIdx.x;
    float s = 0.f;
    #pragma unroll
    for (int i = 0; i < 8; i++) s += separtial[tid + 256 * i];
    red[tid] = s; __syncthreads();
    for (int st = 128; st > 0; st >>= 1) {
        if (tid < st) red[tid] += red[tid + st];
        __syncthreads();
    }
    float lz = logf(red[0]);
    int v = blockIdx.x * 256 + tid;
    if (v < V) logits[v] -= lz;
}

// ---------------------------------------------------------------------------
// ws layout:
//   f32 (float offsets): 0 attn_logits[S] | 2048 cat[2H] | 4096 sumexp(unused)
//     | 4608 u[H] | 5632 x[H] | 6656 separtial[2048]
//     (first 4097 zeroed by prep_kernel; separtial written by every block —
//      no zeroing needed, poison-safe)
//   u16 (byte offsets): 65536 enc_hi(4MB) | +4MB enc_lo | +8MB Ua_hi(2MB)
//     | +10MB Ua_lo(2MB)
// ---------------------------------------------------------------------------
extern "C" void kernel_launch(void* const* d_in, const int* in_sizes, int n_in,
                              void* d_out, int out_size, void* d_ws, size_t ws_size,
                              hipStream_t stream)
{
    const int*   token  = (const int*)d_in[0];
    const float* hidden = (const float*)d_in[1];
    const float* enc    = (const float*)d_in[2];
    const float* emb    = (const float*)d_in[3];
    const float* Ua_w   = (const float*)d_in[4];
    const float* Ua_b   = (const float*)d_in[5];
    const float* Wa_w   = (const float*)d_in[6];
    const float* Wa_b   = (const float*)d_in[7];
    const float* va     = (const float*)d_in[8];
    const float* comb_w = (const float*)d_in[9];
    const float* comb_b = (const float*)d_in[10];
    const float* w_ih   = (const float*)d_in[11];
    const float* w_hh   = (const float*)d_in[12];
    const float* b_ih   = (const float*)d_in[13];
    const float* b_hh   = (const float*)d_in[14];
    const float* out_w  = (const float*)d_in[15];
    const float* out_b  = (const float*)d_in[16];
    float* out = (float*)d_out;

    float* ws          = (float*)d_ws;
    float* attn_logits = ws + 0;
    float* cat         = ws + 2048;
    float* u_vec       = ws + 4608;
    float* x_vec       = ws + 5632;
    float* separtial   = ws + 6656;

    char* wsb   = (char*)d_ws;
    u16* enc_hi = (u16*)(wsb + 65536);
    u16* enc_lo = (u16*)(wsb + 65536 + 4u * 1024 * 1024);
    u16* Ua_hi  = (u16*)(wsb + 65536 + 8u * 1024 * 1024);
    u16* Ua_lo  = (u16*)(wsb + 65536 + 10u * 1024 * 1024);

    // ws zeroing + u-vec matvec + bf16 hi/lo split of enc and Ua
    prep_kernel<<<3328, 256, 0, stream>>>(Wa_w, hidden, Wa_b, Ua_b, u_vec, ws,
                                          enc, Ua_w, enc_hi, enc_lo, Ua_hi, Ua_lo);
    // attention logits (split-bf16 MFMA + tanh/va epilogue)
    attn_scores_kernel<<<256, 256, 0, stream>>>(enc_hi, enc_lo, Ua_hi, Ua_lo,
                                                va, u_vec, attn_logits);
    // fused softmax (per-block recompute) + context -> cat[0:H], attn out slot
    softmax_context_kernel<<<128, 256, 0, stream>>>(attn_logits, enc, cat,
                                                    out + V + H);
    // x = relu(comb_w @ [emb[token]; context] + comb_b)
    matvec_kernel<<<256, 256, 0, stream>>>(comb_w, emb, token, H, cat, H,
                                           comb_b, x_vec, H, 1);
    // fused GRU matvecs + gates -> h_new (cat[H:2H] + d_out hidden slot)
    gru_fused_kernel<<<256, 256, 0, stream>>>(w_ih, w_hh, x_vec, hidden,
                                              b_ih, b_hh, cat + H, out + V);
    // out projection -> logits in d_out[0:V] + per-block sum(exp) partials
    out_matvec_kernel<<<2048, 256, 0, stream>>>(out_w, out_b, cat, out, separtial);
    // log-softmax finalize in place (reduces partials per block)
    logsoftmax_kernel<<<(V + 255) / 256, 256, 0, stream>>>(out, separtial);
}